// Round 2
// baseline (69.052 us; speedup 1.0000x reference)
//
#include <hip/hip_runtime.h>

// 6-qubit statevector, real arithmetic (RY-only circuit; the CCC-Y block is a
// sign+reversal permutation on the isolated q3q4q5=111 sector, global phase i
// drops out of |.|^2).
//
// Layout (round 2): 8 lanes per batch element.
//   lane  = q0*4 + q1*2 + q2   (lane bits: q0->4, q1->2, q2->1)
//   reg r = q3*4 + q4*2 + q5   (st[r], r = 0..7, register-resident)
// Gates on q3/q4/q5: in-register pair updates (controls on q0..2 fold into
// coefficients; controls on q3..5 restrict pairs at compile time).
// Gates on q0/q1/q2: cross-lane via __shfl_xor (controls on q0..2 fold into
// coefficients; no such gate has a control on q3..5).

template <int TB, int CB>  // target bit, in-register control bit (0 = none)
__device__ __forceinline__ void ry_r(float* st, float c, float s) {
#pragma unroll
    for (int r = 0; r < 8; ++r) {
        if (r & TB) continue;
        if (CB && !(r & CB)) continue;
        float a0 = st[r], a1 = st[r + TB];
        st[r]      = fmaf(c, a0, -(s * a1));
        st[r + TB] = fmaf(s, a0, c * a1);
    }
}

template <int TB, int LCM>  // lane-controlled in-register gate
__device__ __forceinline__ void gate_r(float* st, int lane, float c, float s) {
    if (LCM) {
        bool act = (lane & LCM) == LCM;
        c = act ? c : 1.0f;
        s = act ? s : 0.0f;
    }
    ry_r<TB, 0>(st, c, s);
}

template <int XM>  // cross-lane core: st = c*st + ssgn*partner
__device__ __forceinline__ void ry_x(float* st, float c, float ssgn) {
#pragma unroll
    for (int r = 0; r < 8; ++r) {
        float pr = __shfl_xor(st[r], XM);
        st[r] = fmaf(c, st[r], ssgn * pr);
    }
}

template <int XM, int LCM>  // cross-lane gate w/ optional lane control
__device__ __forceinline__ void gate_x(float* st, int lane, float c, float s) {
    float ssgn = (lane & XM) ? s : -s;  // bit0 side: c*a0 - s*a1; bit1: +s
    if (LCM) {
        bool act = (lane & LCM) == LCM;
        c = act ? c : 1.0f;
        ssgn = act ? ssgn : 0.0f;
    }
    ry_x<XM>(st, c, ssgn);
}

__global__ __launch_bounds__(256) void pnn_kernel(const float* __restrict__ x,
                                                  const float* __restrict__ p,
                                                  float* __restrict__ out,
                                                  int n) {
    int gtid = blockIdx.x * blockDim.x + threadIdx.x;
    int e = gtid >> 3;
    int lane = gtid & 7;
    if (e >= n) return;
    float xv = x[e];

    float st[8];
#pragma unroll
    for (int r = 0; r < 8; ++r) st[r] = 0.0f;
    if (lane == 0) st[0] = 1.0f;

    float c, s;
    auto cs = [&](float th) { __sincosf(th * 0.5f, &s, &c); };

    // -- data encoding block 1 + variational layer (targets q0,q1,q2) --
    cs(xv * 3.0f); gate_x<4, 0>(st, lane, c, s);
    cs(xv * 9.0f); gate_x<2, 0>(st, lane, c, s);
    cs(xv);        gate_x<1, 0>(st, lane, c, s);
    cs(p[0]); gate_x<4, 0>(st, lane, c, s);
    cs(p[1]); gate_x<2, 0>(st, lane, c, s);
    cs(p[2]); gate_x<1, 0>(st, lane, c, s);
    // -- controlled rotations onto q3 (reg TB=4); controls q2,q1,q0 = lane 1,2,4
    cs(p[3]); gate_r<4, 1>(st, lane, c, s);
    cs(p[4]); gate_r<4, 2>(st, lane, c, s);
    cs(p[5]); gate_r<4, 4>(st, lane, c, s);
    cs(p[6]); gate_r<4, 0>(st, lane, c, s);
    // -- q4 (TB=2) --
    cs(p[7]);  gate_r<2, 1>(st, lane, c, s);
    cs(p[8]);  gate_r<2, 2>(st, lane, c, s);
    cs(p[9]);  gate_r<2, 4>(st, lane, c, s);
    cs(p[10]); gate_r<2, 0>(st, lane, c, s);
    // -- q5 (TB=1) --
    cs(p[11]); gate_r<1, 1>(st, lane, c, s);
    cs(p[12]); gate_r<1, 2>(st, lane, c, s);
    cs(p[13]); gate_r<1, 4>(st, lane, c, s);
    cs(p[14]); gate_r<1, 0>(st, lane, c, s);
    // -- RY(0.5) on q3,q4,q5 --
    cs(0.5f);
    ry_r<4, 0>(st, c, s); ry_r<2, 0>(st, c, s); ry_r<1, 0>(st, c, s);
    // -- entangling block among q3,q4,q5 (in-register controls) --
    cs(p[15]); ry_r<2, 4>(st, c, s);  // t4 c3
    cs(p[16]); ry_r<1, 4>(st, c, s);  // t5 c3
    cs(p[17]); ry_r<4, 2>(st, c, s);  // t3 c4
    cs(p[18]); ry_r<1, 2>(st, c, s);  // t5 c4
    cs(p[19]); ry_r<4, 1>(st, c, s);  // t3 c5
    cs(p[20]); ry_r<2, 1>(st, c, s);  // t4 c5
    cs(p[21]); ry_r<4, 0>(st, c, s);
    cs(p[22]); ry_r<2, 0>(st, c, s);
    cs(p[23]); ry_r<1, 0>(st, c, s);

    // -- triply-controlled Y on q0,q1,q2: sector r=7 only.
    // new st[7](lane j) = (-1)^popcount(j) * old st[7](lane 7-j); phase i drops.
    {
        float ysign = (__popc(lane) & 1) ? -1.0f : 1.0f;
        float pr = __shfl_xor(st[7], 7);
        st[7] = ysign * pr;
    }

    // -- data encoding block 2 + variational + const (targets q0,q1,q2) --
    cs(xv * 7.0f);  gate_x<4, 0>(st, lane, c, s);
    cs(xv * 17.0f); gate_x<2, 0>(st, lane, c, s);
    cs(xv);         gate_x<1, 0>(st, lane, c, s);
    cs(p[24]); gate_x<4, 0>(st, lane, c, s);
    cs(p[25]); gate_x<2, 0>(st, lane, c, s);
    cs(p[26]); gate_x<1, 0>(st, lane, c, s);
    cs(-0.5f);
    gate_x<4, 0>(st, lane, c, s);
    gate_x<2, 0>(st, lane, c, s);
    gate_x<1, 0>(st, lane, c, s);
    // -- entangling block among q0,q1,q2 (lane controls) --
    cs(p[27]); gate_x<2, 4>(st, lane, c, s);  // t1 c0
    cs(p[28]); gate_x<1, 4>(st, lane, c, s);  // t2 c0
    cs(p[29]); gate_x<4, 2>(st, lane, c, s);  // t0 c1
    cs(p[30]); gate_x<1, 2>(st, lane, c, s);  // t2 c1
    cs(p[31]); gate_x<4, 1>(st, lane, c, s);  // t0 c2
    cs(p[32]); gate_x<2, 1>(st, lane, c, s);  // t1 c2
    cs(p[33]); gate_x<4, 0>(st, lane, c, s);
    cs(p[34]); gate_x<2, 0>(st, lane, c, s);
    cs(p[35]); gate_x<1, 0>(st, lane, c, s);

    // p000 = sum over r at lane 0; p111 = sum over r at lane 7.
    float psum = 0.0f;
#pragma unroll
    for (int r = 0; r < 8; ++r) psum = fmaf(st[r], st[r], psum);
    float other = __shfl_xor(psum, 7);  // lane0 <- lane7's sum (= p111)
    if (lane == 0) out[e] = (other - psum) * 2.0f;
}

extern "C" void kernel_launch(void* const* d_in, const int* in_sizes, int n_in,
                              void* d_out, int out_size, void* d_ws, size_t ws_size,
                              hipStream_t stream) {
    const float* x = (const float*)d_in[0];
    const float* p = (const float*)d_in[1];
    float* out = (float*)d_out;
    int n = in_sizes[0];
    long long threads = (long long)n * 8;
    int block = 256;
    int grid = (int)((threads + block - 1) / block);
    pnn_kernel<<<grid, block, 0, stream>>>(x, p, out, n);
}

// Round 3
// 65.064 us; speedup vs baseline: 1.0613x; 1.0613x over previous
//
#include <hip/hip_runtime.h>

// 6-qubit statevector, real arithmetic. RY-only circuit: state stays real;
// the CCC-Y block touches only the isolated q3q4q5=111 sector and reduces to
// a sign+reversal lane permutation (global phase i drops out of |.|^2).
//
// Layout: 8 lanes per batch element.
//   lane  = q0*4 + q1*2 + q2   (lane bits: q0->4, q1->2, q2->1)
//   reg r = q3*4 + q4*2 + q5   (st[0..7] register-resident)
// Gates targeting q3/q4/q5: in-register pair updates (controls on q0..2 fold
// into per-lane coefficients; controls on q3..5 restrict pairs statically).
// Gates targeting q0/q1/q2: cross-lane via DPP (xor1/xor2/xor7) or ds_swizzle
// (xor4) — DPP is full-rate VALU, no LDS pipe (round-2 shfl_xor was LDS-bound).
//
// Gate fusion (adjacent-modulo-disjoint-qubits RYs fold):
//   block1: RY(3x)+RY(p0) -> RY(3x+p0), etc.
//   q3/q4/q5: RY(p6)+RY(0.5) -> RY(p6+0.5), etc.
//   block2: RY(7x)+RY(p24)+RY(-0.5) -> RY(7x+p24-0.5), etc.

template <int XM>
__device__ __forceinline__ float lane_perm(float v) {
    int i = __float_as_int(v);
    int r;
    if constexpr (XM == 1)
        r = __builtin_amdgcn_update_dpp(i, i, 0xB1, 0xF, 0xF, 0);  // quad_perm [1,0,3,2]
    else if constexpr (XM == 2)
        r = __builtin_amdgcn_update_dpp(i, i, 0x4E, 0xF, 0xF, 0);  // quad_perm [2,3,0,1]
    else if constexpr (XM == 4)
        r = __builtin_amdgcn_ds_swizzle(i, 0x101F);                // xor 4, and 0x1F
    else
        r = __builtin_amdgcn_update_dpp(i, i, 0x141, 0xF, 0xF, 0); // row_half_mirror = xor7
    return __int_as_float(r);
}

template <int TB, int CB>  // in-register gate: target bit, control bit (0=none)
__device__ __forceinline__ void ry_r(float* st, float c, float s) {
#pragma unroll
    for (int r = 0; r < 8; ++r) {
        if (r & TB) continue;
        if (CB && !(r & CB)) continue;
        float a0 = st[r], a1 = st[r + TB];
        st[r]      = fmaf(c, a0, -(s * a1));
        st[r + TB] = fmaf(s, a0, c * a1);
    }
}

template <int TB, int LCM>  // in-register gate with lane (q0..2) control
__device__ __forceinline__ void gate_r(float* st, int lane, float c, float s) {
    if (LCM) {
        bool act = (lane & LCM) == LCM;
        c = act ? c : 1.0f;
        s = act ? s : 0.0f;
    }
    ry_r<TB, 0>(st, c, s);
}

template <int XM, int LCM>  // cross-lane gate (target in q0..2), optional lane control
__device__ __forceinline__ void gate_x(float* st, int lane, float c, float s) {
    float ssgn = (lane & XM) ? s : -s;  // bit0 side: c*a0 - s*a1 ; bit1: s*a0 + c*a1
    if (LCM) {
        bool act = (lane & LCM) == LCM;
        c = act ? c : 1.0f;
        ssgn = act ? ssgn : 0.0f;
    }
#pragma unroll
    for (int r = 0; r < 8; ++r) {
        float pr = lane_perm<XM>(st[r]);
        st[r] = fmaf(c, st[r], ssgn * pr);
    }
}

__global__ __launch_bounds__(256) void pnn_kernel(const float* __restrict__ x,
                                                  const float* __restrict__ p,
                                                  float* __restrict__ out,
                                                  int n) {
    int gtid = blockIdx.x * blockDim.x + threadIdx.x;
    int e = gtid >> 3;
    int lane = gtid & 7;
    if (e >= n) return;
    float xv = x[e];

    float st[8];
#pragma unroll
    for (int r = 0; r < 8; ++r) st[r] = 0.0f;
    if (lane == 0) st[0] = 1.0f;

    float c, s;
    auto cs = [&](float th) { __sincosf(th * 0.5f, &s, &c); };

    // -- block 1: encoding + variational fused (targets q0,q1,q2) --
    cs(fmaf(xv, 3.0f, p[0])); gate_x<4, 0>(st, lane, c, s);
    cs(fmaf(xv, 9.0f, p[1])); gate_x<2, 0>(st, lane, c, s);
    cs(xv + p[2]);            gate_x<1, 0>(st, lane, c, s);
    // -- controlled rotations onto q3 (TB=4); lane controls q2->1, q1->2, q0->4
    cs(p[3]);        gate_r<4, 1>(st, lane, c, s);
    cs(p[4]);        gate_r<4, 2>(st, lane, c, s);
    cs(p[5]);        gate_r<4, 4>(st, lane, c, s);
    cs(p[6] + 0.5f); ry_r<4, 0>(st, c, s);        // RY(p6) fused with RY(0.5)
    // -- q4 (TB=2) --
    cs(p[7]);         gate_r<2, 1>(st, lane, c, s);
    cs(p[8]);         gate_r<2, 2>(st, lane, c, s);
    cs(p[9]);         gate_r<2, 4>(st, lane, c, s);
    cs(p[10] + 0.5f); ry_r<2, 0>(st, c, s);
    // -- q5 (TB=1) --
    cs(p[11]);        gate_r<1, 1>(st, lane, c, s);
    cs(p[12]);        gate_r<1, 2>(st, lane, c, s);
    cs(p[13]);        gate_r<1, 4>(st, lane, c, s);
    cs(p[14] + 0.5f); ry_r<1, 0>(st, c, s);
    // -- entangling block among q3,q4,q5 (register controls) --
    cs(p[15]); ry_r<2, 4>(st, c, s);  // t4 c3
    cs(p[16]); ry_r<1, 4>(st, c, s);  // t5 c3
    cs(p[17]); ry_r<4, 2>(st, c, s);  // t3 c4
    cs(p[18]); ry_r<1, 2>(st, c, s);  // t5 c4
    cs(p[19]); ry_r<4, 1>(st, c, s);  // t3 c5
    cs(p[20]); ry_r<2, 1>(st, c, s);  // t4 c5
    cs(p[21]); ry_r<4, 0>(st, c, s);
    cs(p[22]); ry_r<2, 0>(st, c, s);
    cs(p[23]); ry_r<1, 0>(st, c, s);

    // -- triply-controlled Y on q0,q1,q2: sector r=7 only.
    // new st[7](lane j) = (-1)^popcount(j) * old st[7](lane j^7); phase i drops.
    {
        float ysign = (__popc(lane) & 1) ? -1.0f : 1.0f;
        st[7] = ysign * lane_perm<7>(st[7]);
    }

    // -- block 2: encoding + variational + RY(-0.5), triple-fused --
    cs(fmaf(xv, 7.0f, p[24]) - 0.5f);  gate_x<4, 0>(st, lane, c, s);
    cs(fmaf(xv, 17.0f, p[25]) - 0.5f); gate_x<2, 0>(st, lane, c, s);
    cs(xv + p[26] - 0.5f);             gate_x<1, 0>(st, lane, c, s);
    // -- entangling block among q0,q1,q2 (lane controls) --
    cs(p[27]); gate_x<2, 4>(st, lane, c, s);  // t1 c0
    cs(p[28]); gate_x<1, 4>(st, lane, c, s);  // t2 c0
    cs(p[29]); gate_x<4, 2>(st, lane, c, s);  // t0 c1
    cs(p[30]); gate_x<1, 2>(st, lane, c, s);  // t2 c1
    cs(p[31]); gate_x<4, 1>(st, lane, c, s);  // t0 c2
    cs(p[32]); gate_x<2, 1>(st, lane, c, s);  // t1 c2
    cs(p[33]); gate_x<4, 0>(st, lane, c, s);
    cs(p[34]); gate_x<2, 0>(st, lane, c, s);
    cs(p[35]); gate_x<1, 0>(st, lane, c, s);

    // p000 = lane 0's sum of squares; p111 = lane 7's. Exchange via xor7 DPP.
    float psum = 0.0f;
#pragma unroll
    for (int r = 0; r < 8; ++r) psum = fmaf(st[r], st[r], psum);
    float other = lane_perm<7>(psum);  // lane0 <- lane7 (= p111)
    if (lane == 0) out[e] = (other - psum) * 2.0f;
}

extern "C" void kernel_launch(void* const* d_in, const int* in_sizes, int n_in,
                              void* d_out, int out_size, void* d_ws, size_t ws_size,
                              hipStream_t stream) {
    const float* x = (const float*)d_in[0];
    const float* p = (const float*)d_in[1];
    float* out = (float*)d_out;
    int n = in_sizes[0];
    long long threads = (long long)n * 8;
    int block = 256;
    int grid = (int)((threads + block - 1) / block);
    pnn_kernel<<<grid, block, 0, stream>>>(x, p, out, n);
}